// Round 1
// baseline (2496.767 us; speedup 1.0000x reference)
//
#include <hip/hip_runtime.h>
#include <cstddef>
#include <cstdint>

// Problem constants: B=32 C=192 H=W=64 HEADS=6 WS=8 SHIFT=4 P=8 EMB=640
// HID=768 GROUPS=32, N=64 tokens/window, NW=64 windows/image.
#define SCALE_Q 0.17677669529663688f   // (C/HEADS)^-0.5 = 1/sqrt(32)

__device__ __forceinline__ float gelu_(float x) {
  return 0.5f * x * (1.f + erff(x * 0.70710678118654752f));
}

// ------------------- K0: s = silu(t) @ ada_w.T + ada_b -------------------
// grid (32, 2) block 64
__global__ void k_scales(const float* __restrict__ t,
                         const float* __restrict__ w_msa, const float* __restrict__ b_msa,
                         const float* __restrict__ w_mlp, const float* __restrict__ b_mlp,
                         float* __restrict__ S) {
  int b = blockIdx.x, sel = blockIdx.y;
  const float* W  = sel ? w_mlp : w_msa;
  const float* BV = sel ? b_mlp : b_msa;
  __shared__ float st[640];
  for (int i = threadIdx.x; i < 640; i += 64) {
    float v = t[b * 640 + i];
    st[i] = v / (1.f + __expf(-v));
  }
  __syncthreads();
  int f = threadIdx.x;
  if (f < 40) {
    float acc = BV[f];
    for (int e = 0; e < 640; e++) acc += st[e] * W[f * 640 + e];
    S[(sel * 32 + b) * 40 + f] = acc;
  }
}

// ------------------- K1: build M_b (64x64) from s (8x5) -------------------
// y = irfft2(rfft2(x) * s)  ==  M_b @ x  (per 8x8 patch, p=a*8+b_, q=c*8+d)
// M[p][q] = (1/64) sum_u [ (s[u,0] + (-1)^(b+d) s[u,4]) cos(pi/4 * u*da)
//                        + 2 sum_{v=1..3} s[u,v] cos(pi/4 * (u*da + v*db)) ]
// grid (32, 2) block 256
__global__ void k_mbuild(const float* __restrict__ S, float* __restrict__ M) {
  int b = blockIdx.x, sel = blockIdx.y;
  __shared__ float sl[40];
  __shared__ float ct[8];
  if (threadIdx.x < 40) sl[threadIdx.x] = S[(sel * 32 + b) * 40 + threadIdx.x];
  if (threadIdx.x < 8) ct[threadIdx.x] = cosf(0.78539816339744831f * (float)threadIdx.x);
  __syncthreads();
  float* Mo = M + ((size_t)(sel * 32 + b)) * 4096;
  for (int e = threadIdx.x; e < 4096; e += 256) {
    int p = e >> 6, q = e & 63;
    int a = p >> 3, bb = p & 7, c = q >> 3, d = q & 7;
    int da = (a - c) & 7, db = (bb - d) & 7;
    float sgn = ((bb ^ d) & 1) ? -1.f : 1.f;
    float acc = 0.f;
#pragma unroll
    for (int u = 0; u < 8; u++) {
      float c0 = ct[(u * da) & 7];
      acc += (sl[u * 5 + 0] + sgn * sl[u * 5 + 4]) * c0;
      acc += 2.f * (sl[u * 5 + 1] * ct[(u * da + db) & 7]
                  + sl[u * 5 + 2] * ct[(u * da + 2 * db) & 7]
                  + sl[u * 5 + 3] * ct[(u * da + 3 * db) & 7]);
    }
    Mo[e] = acc * 0.015625f;
  }
}

// ------------------- K2: GroupNorm stats -------------------
// grid 1024 (= b*32+g), block 256; 6 ch * 4096 px = 24576 contiguous floats
__global__ void k_gnstats(const float* __restrict__ X, float* __restrict__ stats) {
  int bg = blockIdx.x;
  const float* base = X + (size_t)bg * 24576;
  float s = 0.f, ss = 0.f;
  for (int i = threadIdx.x; i < 24576; i += 256) {
    float v = base[i];
    s += v; ss += v * v;
  }
  for (int o = 32; o; o >>= 1) { s += __shfl_down(s, o); ss += __shfl_down(ss, o); }
  __shared__ float red[8];
  int wv = threadIdx.x >> 6;
  if ((threadIdx.x & 63) == 0) { red[wv] = s; red[4 + wv] = ss; }
  __syncthreads();
  if (threadIdx.x == 0) {
    float Sv = red[0] + red[1] + red[2] + red[3];
    float SS = red[4] + red[5] + red[6] + red[7];
    float mean = Sv * (1.f / 24576.f);
    float var = SS * (1.f / 24576.f) - mean * mean;
    stats[bg * 2] = mean;
    stats[bg * 2 + 1] = rsqrtf(var + 1e-5f);
  }
}

// ------------------- K3: fused GN-apply + AdaFM (per channel plane) -------------------
// grid (192 c, 32 b) block 256. One block = one 64x64 plane = 64 patches.
// Y[p][patch] = sum_q M[p][q] * Xgn[q][patch]   (64x64x64 GEMM in LDS)
__global__ __launch_bounds__(256) void k_gn_adafm(
    const float* __restrict__ X, const float* __restrict__ stats,
    const float* __restrict__ gw, const float* __restrict__ gb,
    const float* __restrict__ Mmat, float* __restrict__ Hout) {
  int c = blockIdx.x, b = blockIdx.y;
  __shared__ float Ms[64 * 68];  // Ms[q][p] = M[p][q], padded stride 68
  __shared__ float Xs[64 * 68];  // Xs[q][patch]
  const float* Mb = Mmat + (size_t)b * 4096;
  for (int i = threadIdx.x; i < 4096; i += 256) {
    int p = i >> 6, q = i & 63;
    Ms[q * 68 + p] = Mb[i];
  }
  int g = c / 6;
  float mean = stats[(b * 32 + g) * 2];
  float rstd = stats[(b * 32 + g) * 2 + 1];
  float gamma = gw[c], beta = gb[c];
  const float* plane = X + ((size_t)b * 192 + c) * 4096;
  for (int i = threadIdx.x; i < 4096; i += 256) {
    float v = (plane[i] - mean) * rstd * gamma + beta;
    int ph = i >> 9, a = (i >> 6) & 7, pw = (i >> 3) & 7, bb = i & 7;
    Xs[(a * 8 + bb) * 68 + (ph * 8 + pw)] = v;
  }
  __syncthreads();
  int tx = threadIdx.x & 15, ty = threadIdx.x >> 4;
  float acc[4][4] = {};
#pragma unroll
  for (int k = 0; k < 64; k++) {
    float4 a4 = *(const float4*)&Ms[k * 68 + ty * 4];
    float4 b4 = *(const float4*)&Xs[k * 68 + tx * 4];
    float ar[4] = {a4.x, a4.y, a4.z, a4.w};
    float br[4] = {b4.x, b4.y, b4.z, b4.w};
#pragma unroll
    for (int i = 0; i < 4; i++)
#pragma unroll
      for (int j = 0; j < 4; j++)
        acc[i][j] = fmaf(ar[i], br[j], acc[i][j]);
  }
  __syncthreads();
#pragma unroll
  for (int i = 0; i < 4; i++)
#pragma unroll
    for (int j = 0; j < 4; j++)
      Xs[(ty * 4 + i) * 68 + tx * 4 + j] = acc[i][j];
  __syncthreads();
  float* oplane = Hout + ((size_t)b * 192 + c) * 4096;
  for (int i = threadIdx.x; i < 4096; i += 256) {
    int ph = i >> 9, a = (i >> 6) & 7, pw = (i >> 3) & 7, bb = i & 7;
    oplane[i] = Xs[(a * 8 + bb) * 68 + (ph * 8 + pw)];
  }
}

// ------------------- K4: roll(-4,-4) + window partition -> (tokens, C) -------------------
// grid 2048 (windows), block 256
__global__ void k_repack(const float* __restrict__ H, float* __restrict__ XW) {
  int bw = blockIdx.x;
  int b = bw >> 6, w = bw & 63, wh = w >> 3, ww = w & 7;
  __shared__ float T[64 * 193];
  const float* hb = H + (size_t)b * 192 * 4096;
  for (int i = threadIdx.x; i < 64 * 192; i += 256) {
    int ch = i >> 6, n = i & 63;
    int ii = n >> 3, jj = n & 7;
    int hh = (wh * 8 + ii + 4) & 63, wx = (ww * 8 + jj + 4) & 63;
    T[n * 193 + ch] = hb[(size_t)ch * 4096 + hh * 64 + wx];
  }
  __syncthreads();
  float* ob = XW + (size_t)bw * 64 * 192;
  for (int i = threadIdx.x; i < 64 * 192; i += 256) {
    int n = i / 192, ch = i % 192;
    ob[i] = T[n * 193 + ch];
  }
}

// ------------------- K5: GEMM  C[m][n] = sum_k A[m][k]*Bw[n][k] + bias[n] ----------
// grid (M/64, N/64), block 256, 4x4 microtiles
__global__ __launch_bounds__(256) void k_gemm_tn(
    const float* __restrict__ A, const float* __restrict__ Bw,
    const float* __restrict__ bias, float* __restrict__ C, int N, int K) {
  __shared__ float As[16 * 64];
  __shared__ float Bs[16 * 64];
  int m0 = blockIdx.x * 64, n0 = blockIdx.y * 64;
  int tid = threadIdx.x;
  int lrow = tid >> 2, lc4 = (tid & 3) << 2;
  int tx = tid & 15, ty = tid >> 4;
  float acc[4][4] = {};
  for (int k0 = 0; k0 < K; k0 += 16) {
    float4 av = *(const float4*)(A + (size_t)(m0 + lrow) * K + k0 + lc4);
    float4 bv = *(const float4*)(Bw + (size_t)(n0 + lrow) * K + k0 + lc4);
    __syncthreads();
    As[(lc4 + 0) * 64 + lrow] = av.x;
    As[(lc4 + 1) * 64 + lrow] = av.y;
    As[(lc4 + 2) * 64 + lrow] = av.z;
    As[(lc4 + 3) * 64 + lrow] = av.w;
    Bs[(lc4 + 0) * 64 + lrow] = bv.x;
    Bs[(lc4 + 1) * 64 + lrow] = bv.y;
    Bs[(lc4 + 2) * 64 + lrow] = bv.z;
    Bs[(lc4 + 3) * 64 + lrow] = bv.w;
    __syncthreads();
#pragma unroll
    for (int kk = 0; kk < 16; kk++) {
      float4 a4 = *(const float4*)&As[kk * 64 + ty * 4];
      float4 b4 = *(const float4*)&Bs[kk * 64 + tx * 4];
      float ar[4] = {a4.x, a4.y, a4.z, a4.w};
      float br[4] = {b4.x, b4.y, b4.z, b4.w};
#pragma unroll
      for (int i = 0; i < 4; i++)
#pragma unroll
        for (int j = 0; j < 4; j++)
          acc[i][j] = fmaf(ar[i], br[j], acc[i][j]);
    }
  }
#pragma unroll
  for (int i = 0; i < 4; i++) {
    size_t off = (size_t)(m0 + ty * 4 + i) * N + n0 + tx * 4;
    float4 r;
    r.x = acc[i][0] + bias[n0 + tx * 4 + 0];
    r.y = acc[i][1] + bias[n0 + tx * 4 + 1];
    r.z = acc[i][2] + bias[n0 + tx * 4 + 2];
    r.w = acc[i][3] + bias[n0 + tx * 4 + 3];
    *(float4*)(C + off) = r;
  }
}

// ------------------- K6: windowed attention -------------------
// grid (512 windows-in-chunk, 6 heads), block 256
__global__ __launch_bounds__(256) void k_attn(
    const float* __restrict__ QKV, const float* __restrict__ rpb,
    float* __restrict__ OUT, int win_base) {
  int bwl = blockIdx.x, head = blockIdx.y;
  __shared__ float qs[64 * 33], ks[64 * 33], vs[64 * 33];
  __shared__ float ss[64 * 65];
  __shared__ float invs[64];
  const float* base = QKV + (size_t)bwl * 64 * 576;
  int tid = threadIdx.x;
  for (int i = tid; i < 512; i += 256) {
    int n = i >> 3, d4 = (i & 7) << 2;
    const float* rp = base + (size_t)n * 576 + d4;
    float4 qv = *(const float4*)(rp + head * 32);
    float4 kv = *(const float4*)(rp + 192 + head * 32);
    float4 vv = *(const float4*)(rp + 384 + head * 32);
    float* qd = &qs[n * 33 + d4];
    qd[0] = qv.x * SCALE_Q; qd[1] = qv.y * SCALE_Q; qd[2] = qv.z * SCALE_Q; qd[3] = qv.w * SCALE_Q;
    float* kd = &ks[n * 33 + d4];
    kd[0] = kv.x; kd[1] = kv.y; kd[2] = kv.z; kd[3] = kv.w;
    float* vd = &vs[n * 33 + d4];
    vd[0] = vv.x; vd[1] = vv.y; vd[2] = vv.z; vd[3] = vv.w;
  }
  __syncthreads();
  int tx = tid & 15, ty = tid >> 4;
  float acc[4][4] = {};
#pragma unroll 8
  for (int d = 0; d < 32; d++) {
    float ar[4], br[4];
#pragma unroll
    for (int i = 0; i < 4; i++) ar[i] = qs[(ty * 4 + i) * 33 + d];
#pragma unroll
    for (int j = 0; j < 4; j++) br[j] = ks[(tx * 4 + j) * 33 + d];
#pragma unroll
    for (int i = 0; i < 4; i++)
#pragma unroll
      for (int j = 0; j < 4; j++)
        acc[i][j] = fmaf(ar[i], br[j], acc[i][j]);
  }
  int w = (win_base + bwl) & 63, wh = w >> 3, ww = w & 7;
#pragma unroll
  for (int i = 0; i < 4; i++) {
    int n = ty * 4 + i;
    int i1 = n >> 3, j1 = n & 7;
    int g1 = ((wh == 7) ? (i1 < 4 ? 1 : 2) : 0) * 3 + ((ww == 7) ? (j1 < 4 ? 1 : 2) : 0);
#pragma unroll
    for (int j = 0; j < 4; j++) {
      int m = tx * 4 + j;
      int i2 = m >> 3, j2 = m & 7;
      int g2 = ((wh == 7) ? (i2 < 4 ? 1 : 2) : 0) * 3 + ((ww == 7) ? (j2 < 4 ? 1 : 2) : 0);
      float bias = rpb[((i1 - i2 + 7) * 15 + (j1 - j2 + 7)) * 6 + head];
      float mv = (g1 != g2) ? -100.f : 0.f;
      ss[n * 65 + m] = acc[i][j] + bias + mv;
    }
  }
  __syncthreads();
  // softmax: 4 lanes per row
  int row = tid >> 2, qt = tid & 3;
  float mx = -1e30f;
  for (int k = 0; k < 16; k++) mx = fmaxf(mx, ss[row * 65 + qt * 16 + k]);
  mx = fmaxf(mx, __shfl_xor(mx, 1));
  mx = fmaxf(mx, __shfl_xor(mx, 2));
  float sum = 0.f;
  for (int k = 0; k < 16; k++) {
    float e = __expf(ss[row * 65 + qt * 16 + k] - mx);
    ss[row * 65 + qt * 16 + k] = e;
    sum += e;
  }
  sum += __shfl_xor(sum, 1);
  sum += __shfl_xor(sum, 2);
  if (qt == 0) invs[row] = 1.f / sum;
  __syncthreads();
  // PV: 2 rows x 4 d per thread
  int tx2 = tid & 7, ty2 = tid >> 3;
  int n0 = ty2 * 2;
  float o0[4] = {}, o1[4] = {};
  for (int m = 0; m < 64; m++) {
    float p0 = ss[n0 * 65 + m], p1 = ss[(n0 + 1) * 65 + m];
#pragma unroll
    for (int dd = 0; dd < 4; dd++) {
      float vvv = vs[m * 33 + tx2 * 4 + dd];
      o0[dd] = fmaf(p0, vvv, o0[dd]);
      o1[dd] = fmaf(p1, vvv, o1[dd]);
    }
  }
  float i0 = invs[n0], i1 = invs[n0 + 1];
  float* ob = OUT + ((size_t)(bwl * 64 + n0)) * 192 + head * 32 + tx2 * 4;
  float4 r0 = {o0[0] * i0, o0[1] * i0, o0[2] * i0, o0[3] * i0};
  float4 r1 = {o1[0] * i1, o1[1] * i1, o1[2] * i1, o1[3] * i1};
  *(float4*)ob = r0;
  *(float4*)(ob + 192) = r1;
}

// ------------------- K7: window reverse + roll(+4,+4) + residual -------------------
// grid 2048, block 256
__global__ void k_unwindow(const float* __restrict__ Y2, const float* __restrict__ X0,
                           float* __restrict__ X1) {
  int bw = blockIdx.x;
  int b = bw >> 6, w = bw & 63, wh = w >> 3, ww = w & 7;
  __shared__ float T[64 * 193];
  const float* yb = Y2 + (size_t)bw * 64 * 192;
  for (int i = threadIdx.x; i < 64 * 192; i += 256) {
    int n = i / 192, ch = i % 192;
    T[n * 193 + ch] = yb[i];
  }
  __syncthreads();
  size_t pb = (size_t)b * 192 * 4096;
  for (int i = threadIdx.x; i < 64 * 192; i += 256) {
    int ch = i >> 6, n = i & 63;
    int ii = n >> 3, jj = n & 7;
    int hh = (wh * 8 + ii + 4) & 63, wx = (ww * 8 + jj + 4) & 63;
    size_t gidx = pb + (size_t)ch * 4096 + hh * 64 + wx;
    X1[gidx] = X0[gidx] + T[n * 193 + ch];
  }
}

// ------------------- K8: feature-major GEMM (MLP) -------------------
// C[m][n] = act(sum_k A[m][k] * X[k][n] + bias[m]) [+ res]
// grid (N/64, M/64, Z batches); mode 0 = gelu, 1 = +residual
__global__ __launch_bounds__(256) void k_gemm_fm(
    const float* __restrict__ A, const float* __restrict__ Xall,
    const float* __restrict__ bias, float* Call, const float* ResAll,
    int N, int K, int mode) {
  __shared__ float As[16 * 64];
  __shared__ float Bs[16 * 64];
  int n0 = blockIdx.x * 64, m0 = blockIdx.y * 64, z = blockIdx.z;
  size_t cstride = (size_t)gridDim.y * 64 * N;
  const float* X = Xall + (size_t)z * K * N;
  float* C = Call + (size_t)z * cstride;
  const float* Res = ResAll ? ResAll + (size_t)z * cstride : nullptr;
  int tid = threadIdx.x;
  int arow = tid >> 2, ac4 = (tid & 3) << 2;
  int brow = tid >> 4, bc4 = (tid & 15) << 2;
  int tx = tid & 15, ty = tid >> 4;
  float acc[4][4] = {};
  for (int k0 = 0; k0 < K; k0 += 16) {
    float4 av = *(const float4*)(A + (size_t)(m0 + arow) * K + k0 + ac4);
    float4 bv = *(const float4*)(X + (size_t)(k0 + brow) * N + n0 + bc4);
    __syncthreads();
    As[(ac4 + 0) * 64 + arow] = av.x;
    As[(ac4 + 1) * 64 + arow] = av.y;
    As[(ac4 + 2) * 64 + arow] = av.z;
    As[(ac4 + 3) * 64 + arow] = av.w;
    *(float4*)&Bs[brow * 64 + bc4] = bv;
    __syncthreads();
#pragma unroll
    for (int kk = 0; kk < 16; kk++) {
      float4 a4 = *(const float4*)&As[kk * 64 + ty * 4];
      float4 b4 = *(const float4*)&Bs[kk * 64 + tx * 4];
      float ar[4] = {a4.x, a4.y, a4.z, a4.w};
      float br[4] = {b4.x, b4.y, b4.z, b4.w};
#pragma unroll
      for (int i = 0; i < 4; i++)
#pragma unroll
        for (int j = 0; j < 4; j++)
          acc[i][j] = fmaf(ar[i], br[j], acc[i][j]);
    }
  }
#pragma unroll
  for (int i = 0; i < 4; i++) {
    int m = m0 + ty * 4 + i;
    float bi = bias[m];
    size_t off = (size_t)m * N + n0 + tx * 4;
    float v[4];
#pragma unroll
    for (int j = 0; j < 4; j++) v[j] = acc[i][j] + bi;
    if (mode == 0) {
#pragma unroll
      for (int j = 0; j < 4; j++) v[j] = gelu_(v[j]);
    } else {
      float4 rr = *(const float4*)(Res + off);
      v[0] += rr.x; v[1] += rr.y; v[2] += rr.z; v[3] += rr.w;
    }
    float4 r = {v[0], v[1], v[2], v[3]};
    *(float4*)(C + off) = r;
  }
}

// ------------------- launch -------------------
extern "C" void kernel_launch(void* const* d_in, const int* in_sizes, int n_in,
                              void* d_out, int out_size, void* d_ws, size_t ws_size,
                              hipStream_t stream) {
  (void)in_sizes; (void)n_in; (void)out_size; (void)ws_size;
  const float* x      = (const float*)d_in[0];
  const float* t      = (const float*)d_in[1];
  const float* n1_w   = (const float*)d_in[2];
  const float* n1_b   = (const float*)d_in[3];
  const float* qkv_w  = (const float*)d_in[4];
  const float* qkv_b  = (const float*)d_in[5];
  const float* rpb    = (const float*)d_in[6];
  const float* proj_w = (const float*)d_in[7];
  const float* proj_b = (const float*)d_in[8];
  const float* n2_w   = (const float*)d_in[9];
  const float* n2_b   = (const float*)d_in[10];
  const float* fc1_w  = (const float*)d_in[11];
  const float* fc1_b  = (const float*)d_in[12];
  const float* fc2_w  = (const float*)d_in[13];
  const float* fc2_b  = (const float*)d_in[14];
  const float* aw_msa = (const float*)d_in[15];
  const float* ab_msa = (const float*)d_in[16];
  const float* aw_mlp = (const float*)d_in[17];
  const float* ab_mlp = (const float*)d_in[18];
  float* out = (float*)d_out;
  float* ws = (float*)d_ws;

  // workspace layout (floats); total 95,420,416 floats = 382 MB
  float* S    = ws;               // 2560
  float* M    = ws + 4096;        // 262144 (msa at +0, mlp at +131072)
  float* ST1  = ws + 266240;      // 2048
  float* ST2  = ws + 268288;      // 2048
  float* Hbuf = ws + 1048576;     // 25165824 (h1, then h2)
  float* XW   = ws + 26214400;    // 25165824 (windowed tokens, then Y2)
  float* AO   = ws + 51380224;    // 25165824 (attn out, then fc1-out chunk)
  float* QKVB = ws + 76546048;    // 18874368 (qkv chunk: 8 batches)

  k_scales<<<dim3(32, 2), 64, 0, stream>>>(t, aw_msa, ab_msa, aw_mlp, ab_mlp, S);
  k_mbuild<<<dim3(32, 2), 256, 0, stream>>>(S, M);

  // ---- attention branch ----
  k_gnstats<<<1024, 256, 0, stream>>>(x, ST1);
  k_gn_adafm<<<dim3(192, 32), 256, 0, stream>>>(x, ST1, n1_w, n1_b, M, Hbuf);
  k_repack<<<2048, 256, 0, stream>>>(Hbuf, XW);
  for (int q = 0; q < 4; q++) {
    k_gemm_tn<<<dim3(512, 9), 256, 0, stream>>>(
        XW + (size_t)q * 32768 * 192, qkv_w, qkv_b, QKVB, 576, 192);
    k_attn<<<dim3(512, 6), 256, 0, stream>>>(
        QKVB, rpb, AO + (size_t)q * 32768 * 192, q * 512);
  }
  k_gemm_tn<<<dim3(2048, 3), 256, 0, stream>>>(AO, proj_w, proj_b, XW, 192, 192);
  k_unwindow<<<2048, 256, 0, stream>>>(XW, x, out);

  // ---- MLP branch ----
  k_gnstats<<<1024, 256, 0, stream>>>(out, ST2);
  k_gn_adafm<<<dim3(192, 32), 256, 0, stream>>>(out, ST2, n2_w, n2_b, M + 131072, Hbuf);
  for (int bc = 0; bc < 4; bc++) {
    const float* hsrc = Hbuf + (size_t)bc * 8 * 786432;
    float* osrc = out + (size_t)bc * 8 * 786432;
    k_gemm_fm<<<dim3(64, 12, 8), 256, 0, stream>>>(
        fc1_w, hsrc, fc1_b, AO, nullptr, 4096, 192, 0);
    k_gemm_fm<<<dim3(64, 3, 8), 256, 0, stream>>>(
        fc2_w, AO, fc2_b, osrc, osrc, 4096, 768, 1);
  }
}

// Round 3
// 1208.586 us; speedup vs baseline: 2.0659x; 2.0659x over previous
//
#include <hip/hip_runtime.h>
#include <cstddef>
#include <cstdint>

// B=32 C=192 H=W=64 HEADS=6 WS=8 SHIFT=4 P=8 EMB=640 HID=768 GROUPS=32
#define SCALE_Q 0.17677669529663688f

typedef __attribute__((ext_vector_type(8))) short short8;
typedef __attribute__((ext_vector_type(4))) float f32x4;

__device__ __forceinline__ float gelu_(float x) {
  return 0.5f * x * (1.f + erff(x * 0.70710678118654752f));
}
__device__ __forceinline__ ushort f2b(float x) {
  uint u = __float_as_uint(x);
  return (ushort)((u + 0x7FFFu + ((u >> 16) & 1u)) >> 16);
}

// ------------------- K0: s = silu(t) @ ada_w.T + ada_b -------------------
__global__ void k_scales(const float* __restrict__ t,
                         const float* __restrict__ w_msa, const float* __restrict__ b_msa,
                         const float* __restrict__ w_mlp, const float* __restrict__ b_mlp,
                         float* __restrict__ S) {
  int b = blockIdx.x, sel = blockIdx.y;
  const float* W  = sel ? w_mlp : w_msa;
  const float* BV = sel ? b_mlp : b_msa;
  __shared__ float st[640];
  for (int i = threadIdx.x; i < 640; i += 64) {
    float v = t[b * 640 + i];
    st[i] = v / (1.f + __expf(-v));
  }
  __syncthreads();
  int f = threadIdx.x;
  if (f < 40) {
    float acc = BV[f];
    for (int e = 0; e < 640; e++) acc += st[e] * W[f * 640 + e];
    S[(sel * 32 + b) * 40 + f] = acc;
  }
}

// ------------------- K1: build M_b (64x64) from s (8x5) -------------------
__global__ void k_mbuild(const float* __restrict__ S, float* __restrict__ M) {
  int b = blockIdx.x, sel = blockIdx.y;
  __shared__ float sl[40];
  __shared__ float ct[8];
  if (threadIdx.x < 40) sl[threadIdx.x] = S[(sel * 32 + b) * 40 + threadIdx.x];
  if (threadIdx.x < 8) ct[threadIdx.x] = cosf(0.78539816339744831f * (float)threadIdx.x);
  __syncthreads();
  float* Mo = M + ((size_t)(sel * 32 + b)) * 4096;
  for (int e = threadIdx.x; e < 4096; e += 256) {
    int p = e >> 6, q = e & 63;
    int a = p >> 3, bb = p & 7, c = q >> 3, d = q & 7;
    int da = (a - c) & 7, db = (bb - d) & 7;
    float sgn = ((bb ^ d) & 1) ? -1.f : 1.f;
    float acc = 0.f;
#pragma unroll
    for (int u = 0; u < 8; u++) {
      acc += (sl[u * 5 + 0] + sgn * sl[u * 5 + 4]) * ct[(u * da) & 7];
      acc += 2.f * (sl[u * 5 + 1] * ct[(u * da + db) & 7]
                  + sl[u * 5 + 2] * ct[(u * da + 2 * db) & 7]
                  + sl[u * 5 + 3] * ct[(u * da + 3 * db) & 7]);
    }
    Mo[e] = acc * 0.015625f;
  }
}

// ------------------- K2: weights fp32 -> bf16 -------------------
__global__ void k_f2b(const float* __restrict__ s0, const float* __restrict__ s1,
                      const float* __restrict__ s2, const float* __restrict__ s3,
                      ushort* __restrict__ d0, ushort* __restrict__ d1,
                      ushort* __restrict__ d2, ushort* __restrict__ d3) {
  int g = blockIdx.x * 256 + threadIdx.x;  // one float4 per thread
  const float* s; ushort* d; int off;
  if (g < 27648)       { s = s0; d = d0; off = g * 4; }
  else if (g < 36864)  { s = s1; d = d1; off = (g - 27648) * 4; }
  else if (g < 73728)  { s = s2; d = d2; off = (g - 36864) * 4; }
  else if (g < 110592) { s = s3; d = d3; off = (g - 73728) * 4; }
  else return;
  float4 v = *(const float4*)(s + off);
  ushort4 o = {f2b(v.x), f2b(v.y), f2b(v.z), f2b(v.w)};
  *(ushort4*)(d + off) = o;
}

// ------------------- K3: GroupNorm stats -------------------
__global__ void k_gnstats(const float* __restrict__ X, float* __restrict__ stats) {
  int bg = blockIdx.x;
  const float* base = X + (size_t)bg * 24576;
  float s = 0.f, ss = 0.f;
  for (int i = threadIdx.x; i < 24576; i += 256) {
    float v = base[i];
    s += v; ss += v * v;
  }
  for (int o = 32; o; o >>= 1) { s += __shfl_down(s, o); ss += __shfl_down(ss, o); }
  __shared__ float red[8];
  int wv = threadIdx.x >> 6;
  if ((threadIdx.x & 63) == 0) { red[wv] = s; red[4 + wv] = ss; }
  __syncthreads();
  if (threadIdx.x == 0) {
    float Sv = red[0] + red[1] + red[2] + red[3];
    float SS = red[4] + red[5] + red[6] + red[7];
    float mean = Sv * (1.f / 24576.f);
    float var = SS * (1.f / 24576.f) - mean * mean;
    stats[bg * 2] = mean;
    stats[bg * 2 + 1] = rsqrtf(var + 1e-5f);
  }
}

// ------------------- K4: fused GN-apply + AdaFM, bf16 plane out -------------------
__global__ __launch_bounds__(256) void k_gn_adafm(
    const float* __restrict__ X, const float* __restrict__ stats,
    const float* __restrict__ gw, const float* __restrict__ gb,
    const float* __restrict__ Mmat, ushort* __restrict__ Hout) {
  int c = blockIdx.x, b = blockIdx.y;
  __shared__ float Ms[64 * 68];
  __shared__ float Xs[64 * 68];
  const float* Mb = Mmat + (size_t)b * 4096;
  for (int i = threadIdx.x; i < 4096; i += 256) {
    int p = i >> 6, q = i & 63;
    Ms[q * 68 + p] = Mb[i];
  }
  int g = c / 6;
  float mean = stats[(b * 32 + g) * 2];
  float rstd = stats[(b * 32 + g) * 2 + 1];
  float gamma = gw[c], beta = gb[c];
  const float* plane = X + ((size_t)b * 192 + c) * 4096;
  for (int i = threadIdx.x; i < 4096; i += 256) {
    float v = (plane[i] - mean) * rstd * gamma + beta;
    int ph = i >> 9, a = (i >> 6) & 7, pw = (i >> 3) & 7, bb = i & 7;
    Xs[(a * 8 + bb) * 68 + (ph * 8 + pw)] = v;
  }
  __syncthreads();
  int tx = threadIdx.x & 15, ty = threadIdx.x >> 4;
  float acc[4][4] = {};
#pragma unroll
  for (int k = 0; k < 64; k++) {
    float4 a4 = *(const float4*)&Ms[k * 68 + ty * 4];
    float4 b4 = *(const float4*)&Xs[k * 68 + tx * 4];
    float ar[4] = {a4.x, a4.y, a4.z, a4.w};
    float br[4] = {b4.x, b4.y, b4.z, b4.w};
#pragma unroll
    for (int i = 0; i < 4; i++)
#pragma unroll
      for (int j = 0; j < 4; j++)
        acc[i][j] = fmaf(ar[i], br[j], acc[i][j]);
  }
  __syncthreads();
#pragma unroll
  for (int i = 0; i < 4; i++)
#pragma unroll
    for (int j = 0; j < 4; j++)
      Xs[(ty * 4 + i) * 68 + tx * 4 + j] = acc[i][j];
  __syncthreads();
  ushort* oplane = Hout + ((size_t)b * 192 + c) * 4096;
  for (int ip = threadIdx.x; ip < 2048; ip += 256) {
    int i = ip << 1;
    int ph2 = i >> 9, a = (i >> 6) & 7, pw = (i >> 3) & 7, bb = i & 7;
    float v0 = Xs[(a * 8 + bb) * 68 + (ph2 * 8 + pw)];
    float v1 = Xs[(a * 8 + bb + 1) * 68 + (ph2 * 8 + pw)];
    uint pk = (uint)f2b(v0) | ((uint)f2b(v1) << 16);
    ((uint*)oplane)[ip] = pk;
  }
}

// ------------------- K5: unified MFMA GEMM -------------------
// C[m][n] = A[m][k] * B[n][k]  (A = bf16 weights [Mfull][K], B = bf16 tokens)
// Block tile: 192 (m) x 128 (n tokens). 4 waves: wsm in {0,1} (96 rows), wsn in {0,1} (64 tok).
// A-frags direct from global; B staged in LDS per 32-k step.
// bmode: 0 = token-major rows (stride K); 1 = plane linear (H[c][4096]); 2 = plane windowed.
// emode: 0 = bias->bf16; 1 = bias+gelu->bf16; 2 = bias+res(out RMW) fp32 plane; 3 = bias+res(x) fp32 window-scatter.
__global__ __launch_bounds__(256) void k_gemm(
    const ushort* __restrict__ A, const void* __restrict__ Bsrc,
    const float* __restrict__ bias, void* __restrict__ Cdst,
    const float* __restrict__ Res, int K, int Mfull, int bmode, int emode) {
  __shared__ ushort Bs[128][40];
  __shared__ float Cs[192][68];
  int nt = blockIdx.x, m0 = blockIdx.y * 192, z = blockIdx.z;
  int n0 = nt * 128;
  int tid = threadIdx.x;
  int lane = tid & 63, wv = tid >> 6;
  int wsm = wv & 1, wsn = wv >> 1;
  int lr = lane & 15, lq = lane >> 4;

  f32x4 acc[6][4];
#pragma unroll
  for (int i = 0; i < 6; i++)
#pragma unroll
    for (int j = 0; j < 4; j++) acc[i][j] = 0;

  const ushort* Arow = A + (size_t)(m0 + wsm * 96 + lr) * K + lq * 8;
  const ushort* Btok = (const ushort*)Bsrc + (bmode == 0 ? (size_t)(z * 4096 + n0) * K : 0);
  const ushort* Bpl  = (const ushort*)Bsrc + (size_t)z * 192 * 4096;

  for (int k0 = 0; k0 < K; k0 += 32) {
    __syncthreads();
    if (bmode == 0) {
      // FIX (R2->R3): uint4 moves 8 ushorts, so each 32-wide k-slab needs
      // 4 chunks/row: 512 ids x 8 ushorts = 128 rows x 32 cols, full coverage.
#pragma unroll
      for (int u = 0; u < 2; u++) {
        int id = tid + u * 256;
        int row = id >> 2, ko = (id & 3) << 3;
        *(uint4*)&Bs[row][ko] = *(const uint4*)(Btok + (size_t)row * K + k0 + ko);
      }
    } else {
#pragma unroll
      for (int u = 0; u < 2; u++) {
        int id = tid + u * 256;
        int cc = id >> 4, r8 = (id & 15) << 3;
        const ushort* pl = Bpl + (size_t)(k0 + cc) * 4096;
        ushort tmp[8];
        if (bmode == 1) {
          *(uint4*)tmp = *(const uint4*)(pl + n0 + r8);
        } else {
          int tg = n0 + r8;
          int w = tg >> 6, nn = tg & 63;
          int wh = w >> 3, ww = w & 7, ii = nn >> 3;
          int hh = ((wh << 3) + ii + 4) & 63;
          int wx0 = (ww << 3) + 4;
          int wx1 = ((ww << 3) + 8) & 63;
          *(uint2*)&tmp[0] = *(const uint2*)(pl + hh * 64 + wx0);
          *(uint2*)&tmp[4] = *(const uint2*)(pl + hh * 64 + wx1);
        }
#pragma unroll
        for (int j = 0; j < 8; j++) Bs[r8 + j][cc] = tmp[j];
      }
    }
    __syncthreads();
    short8 bf[4];
#pragma unroll
    for (int j = 0; j < 4; j++)
      bf[j] = *(const short8*)&Bs[wsn * 64 + j * 16 + lr][lq * 8];
#pragma unroll
    for (int i = 0; i < 6; i++) {
      short8 af = *(const short8*)(Arow + (size_t)(i * 16) * K + k0);
#pragma unroll
      for (int j = 0; j < 4; j++)
        acc[i][j] = __builtin_amdgcn_mfma_f32_16x16x32_bf16(af, bf[j], acc[i][j], 0, 0, 0);
    }
  }

  const float* bptr = bias + m0;
  for (int ph = 0; ph < 2; ph++) {
    __syncthreads();
    if (wsn == ph) {
#pragma unroll
      for (int i = 0; i < 6; i++)
#pragma unroll
        for (int j = 0; j < 4; j++) {
          int tokl = j * 16 + lr;
          int f = wsm * 96 + i * 16 + lq * 4;
#pragma unroll
          for (int r = 0; r < 4; r++) Cs[f + r][tokl] = acc[i][j][r];
        }
    }
    __syncthreads();
    int tokbase = z * 4096 + n0 + ph * 64;
    if (emode <= 1) {
      for (int u = tid; u < 768; u += 256) {
        int c4 = (u >> 4) << 2, tq = (u & 15) << 2;
        float4 r0 = *(const float4*)&Cs[c4 + 0][tq];
        float4 r1 = *(const float4*)&Cs[c4 + 1][tq];
        float4 r2 = *(const float4*)&Cs[c4 + 2][tq];
        float4 r3 = *(const float4*)&Cs[c4 + 3][tq];
        float b0 = bptr[c4], b1 = bptr[c4 + 1], b2 = bptr[c4 + 2], b3 = bptr[c4 + 3];
        float vr[4][4] = {{r0.x + b0, r1.x + b1, r2.x + b2, r3.x + b3},
                          {r0.y + b0, r1.y + b1, r2.y + b2, r3.y + b3},
                          {r0.z + b0, r1.z + b1, r2.z + b2, r3.z + b3},
                          {r0.w + b0, r1.w + b1, r2.w + b2, r3.w + b3}};
#pragma unroll
        for (int jj = 0; jj < 4; jj++) {
          float v0 = vr[jj][0], v1 = vr[jj][1], v2 = vr[jj][2], v3 = vr[jj][3];
          if (emode == 1) { v0 = gelu_(v0); v1 = gelu_(v1); v2 = gelu_(v2); v3 = gelu_(v3); }
          ushort4 o = {f2b(v0), f2b(v1), f2b(v2), f2b(v3)};
          *(ushort4*)((ushort*)Cdst + (size_t)(tokbase + tq + jj) * Mfull + m0 + c4) = o;
        }
      }
    } else if (emode == 2) {
      for (int u = tid; u < 3072; u += 256) {
        int cc = u >> 4, tq = (u & 15) << 2;
        size_t addr = ((size_t)z * 192 + cc) * 4096 + n0 + ph * 64 + tq;
        float4 rr = *(const float4*)(Res + addr);
        float4 cv = *(const float4*)&Cs[cc][tq];
        float bi = bptr[cc];
        float4 ov = {cv.x + bi + rr.x, cv.y + bi + rr.y, cv.z + bi + rr.z, cv.w + bi + rr.w};
        *(float4*)((float*)Cdst + addr) = ov;
      }
    } else {
      int tg0 = n0 + ph * 64;
      int w = tg0 >> 6, wh = w >> 3, ww = w & 7;
      for (int u = tid; u < 3072; u += 256) {
        int cc = u >> 4, tq = (u & 15) << 2;
        int ii = tq >> 3;
        int hh = ((wh << 3) + ii + 4) & 63;
        int wx = (tq & 4) ? (((ww << 3) + 8) & 63) : ((ww << 3) + 4);
        size_t addr = ((size_t)z * 192 + cc) * 4096 + hh * 64 + wx;
        float4 rr = *(const float4*)(Res + addr);
        float4 cv = *(const float4*)&Cs[cc][tq];
        float bi = bptr[cc];
        float4 ov = {cv.x + bi + rr.x, cv.y + bi + rr.y, cv.z + bi + rr.z, cv.w + bi + rr.w};
        *(float4*)((float*)Cdst + addr) = ov;
      }
    }
  }
}

// ------------------- K6: windowed attention (bf16 in/out) -------------------
__global__ __launch_bounds__(256) void k_attn(
    const ushort* __restrict__ QKV, const float* __restrict__ rpb,
    ushort* __restrict__ AO) {
  int bw = blockIdx.x, head = blockIdx.y;
  __shared__ float qs[64 * 33], ks[64 * 33], vs[64 * 33];
  __shared__ float ss[64 * 65];
  __shared__ float invs[64];
  const ushort* base = QKV + (size_t)bw * 64 * 576 + head * 32;
  int tid = threadIdx.x;
  {
    int n = tid >> 2, d8 = (tid & 3) << 3;
    const ushort* rp = base + (size_t)n * 576 + d8;
    uint4 qv = *(const uint4*)(rp);
    uint4 kv = *(const uint4*)(rp + 192);
    uint4 vv = *(const uint4*)(rp + 384);
    uint qa[4] = {qv.x, qv.y, qv.z, qv.w};
    uint ka[4] = {kv.x, kv.y, kv.z, kv.w};
    uint va[4] = {vv.x, vv.y, vv.z, vv.w};
    float* qd = &qs[n * 33 + d8];
    float* kd = &ks[n * 33 + d8];
    float* vd = &vs[n * 33 + d8];
#pragma unroll
    for (int i = 0; i < 4; i++) {
      qd[2 * i]     = __uint_as_float(qa[i] << 16) * SCALE_Q;
      qd[2 * i + 1] = __uint_as_float(qa[i] & 0xffff0000u) * SCALE_Q;
      kd[2 * i]     = __uint_as_float(ka[i] << 16);
      kd[2 * i + 1] = __uint_as_float(ka[i] & 0xffff0000u);
      vd[2 * i]     = __uint_as_float(va[i] << 16);
      vd[2 * i + 1] = __uint_as_float(va[i] & 0xffff0000u);
    }
  }
  __syncthreads();
  int tx = tid & 15, ty = tid >> 4;
  float acc[4][4] = {};
#pragma unroll 8
  for (int d = 0; d < 32; d++) {
    float ar[4], br[4];
#pragma unroll
    for (int i = 0; i < 4; i++) ar[i] = qs[(ty * 4 + i) * 33 + d];
#pragma unroll
    for (int j = 0; j < 4; j++) br[j] = ks[(tx * 4 + j) * 33 + d];
#pragma unroll
    for (int i = 0; i < 4; i++)
#pragma unroll
      for (int j = 0; j < 4; j++)
        acc[i][j] = fmaf(ar[i], br[j], acc[i][j]);
  }
  int w = bw & 63, wh = w >> 3, ww = w & 7;
#pragma unroll
  for (int i = 0; i < 4; i++) {
    int n = ty * 4 + i;
    int i1 = n >> 3, j1 = n & 7;
    int g1 = ((wh == 7) ? (i1 < 4 ? 1 : 2) : 0) * 3 + ((ww == 7) ? (j1 < 4 ? 1 : 2) : 0);
#pragma unroll
    for (int j = 0; j < 4; j++) {
      int m = tx * 4 + j;
      int i2 = m >> 3, j2 = m & 7;
      int g2 = ((wh == 7) ? (i2 < 4 ? 1 : 2) : 0) * 3 + ((ww == 7) ? (j2 < 4 ? 1 : 2) : 0);
      float bias = rpb[((i1 - i2 + 7) * 15 + (j1 - j2 + 7)) * 6 + head];
      float mv = (g1 != g2) ? -100.f : 0.f;
      ss[n * 65 + m] = acc[i][j] + bias + mv;
    }
  }
  __syncthreads();
  int row = tid >> 2, qt = tid & 3;
  float mx = -1e30f;
  for (int k = 0; k < 16; k++) mx = fmaxf(mx, ss[row * 65 + qt * 16 + k]);
  mx = fmaxf(mx, __shfl_xor(mx, 1));
  mx = fmaxf(mx, __shfl_xor(mx, 2));
  float sum = 0.f;
  for (int k = 0; k < 16; k++) {
    float e = __expf(ss[row * 65 + qt * 16 + k] - mx);
    ss[row * 65 + qt * 16 + k] = e;
    sum += e;
  }
  sum += __shfl_xor(sum, 1);
  sum += __shfl_xor(sum, 2);
  if (qt == 0) invs[row] = 1.f / sum;
  __syncthreads();
  int tx2 = tid & 7, ty2 = tid >> 3;
  int n0 = ty2 * 2;
  float o0[4] = {}, o1[4] = {};
  for (int m = 0; m < 64; m++) {
    float p0 = ss[n0 * 65 + m], p1 = ss[(n0 + 1) * 65 + m];
#pragma unroll
    for (int dd = 0; dd < 4; dd++) {
      float vvv = vs[m * 33 + tx2 * 4 + dd];
      o0[dd] = fmaf(p0, vvv, o0[dd]);
      o1[dd] = fmaf(p1, vvv, o1[dd]);
    }
  }
  float i0 = invs[n0], i1 = invs[n0 + 1];
  ushort* ob = AO + ((size_t)(bw * 64 + n0)) * 192 + head * 32 + tx2 * 4;
  ushort4 w0 = {f2b(o0[0] * i0), f2b(o0[1] * i0), f2b(o0[2] * i0), f2b(o0[3] * i0)};
  ushort4 w1 = {f2b(o1[0] * i1), f2b(o1[1] * i1), f2b(o1[2] * i1), f2b(o1[3] * i1)};
  *(ushort4*)ob = w0;
  *(ushort4*)(ob + 192) = w1;
}

// ------------------- launch -------------------
extern "C" void kernel_launch(void* const* d_in, const int* in_sizes, int n_in,
                              void* d_out, int out_size, void* d_ws, size_t ws_size,
                              hipStream_t stream) {
  (void)in_sizes; (void)n_in; (void)out_size; (void)ws_size;
  const float* x      = (const float*)d_in[0];
  const float* t      = (const float*)d_in[1];
  const float* n1_w   = (const float*)d_in[2];
  const float* n1_b   = (const float*)d_in[3];
  const float* qkv_w  = (const float*)d_in[4];
  const float* qkv_b  = (const float*)d_in[5];
  const float* rpb    = (const float*)d_in[6];
  const float* proj_w = (const float*)d_in[7];
  const float* proj_b = (const float*)d_in[8];
  const float* n2_w   = (const float*)d_in[9];
  const float* n2_b   = (const float*)d_in[10];
  const float* fc1_w  = (const float*)d_in[11];
  const float* fc1_b  = (const float*)d_in[12];
  const float* fc2_w  = (const float*)d_in[13];
  const float* fc2_b  = (const float*)d_in[14];
  const float* aw_msa = (const float*)d_in[15];
  const float* ab_msa = (const float*)d_in[16];
  const float* aw_mlp = (const float*)d_in[17];
  const float* ab_mlp = (const float*)d_in[18];
  float* out = (float*)d_out;
  float* ws = (float*)d_ws;

  // workspace layout (float offsets): total 63,438,848 floats = 254 MB
  float*  S   = ws;                          // 2560
  float*  Mm  = ws + 4096;                   // 262144
  float*  ST1 = ws + 266240;                 // 2048
  float*  ST2 = ws + 268288;                 // 2048
  ushort* Wq  = (ushort*)(ws + 270336);      // 110592 bf16
  ushort* Wp  = Wq + 110592;                 // 36864
  ushort* W1  = Wp + 36864;                  // 147456
  ushort* W2  = W1 + 147456;                 // 147456
  ushort* Hbf = (ushort*)(ws + 524288);      // 25165824 bf16 (H planes, both branches)
  ushort* QKV = (ushort*)(ws + 13107200);    // 75497472 bf16
  ushort* AO  = (ushort*)(ws + 50855936);    // 25165824 bf16
  ushort* G   = QKV;                         // 100663296 bf16, aliases QKV+AO (both dead)

  k_scales<<<dim3(32, 2), 64, 0, stream>>>(t, aw_msa, ab_msa, aw_mlp, ab_mlp, S);
  k_mbuild<<<dim3(32, 2), 256, 0, stream>>>(S, Mm);
  k_f2b<<<432, 256, 0, stream>>>(qkv_w, proj_w, fc1_w, fc2_w, Wq, Wp, W1, W2);

  // ---- attention branch ----
  k_gnstats<<<1024, 256, 0, stream>>>(x, ST1);
  k_gn_adafm<<<dim3(192, 32), 256, 0, stream>>>(x, ST1, n1_w, n1_b, Mm, Hbf);
  k_gemm<<<dim3(32, 3, 32), 256, 0, stream>>>(Wq, Hbf, qkv_b, QKV, nullptr, 192, 576, 2, 0);
  k_attn<<<dim3(2048, 6), 256, 0, stream>>>(QKV, rpb, AO);
  k_gemm<<<dim3(32, 1, 32), 256, 0, stream>>>(Wp, AO, proj_b, out, x, 192, 192, 0, 3);

  // ---- MLP branch ----
  k_gnstats<<<1024, 256, 0, stream>>>(out, ST2);
  k_gn_adafm<<<dim3(192, 32), 256, 0, stream>>>(out, ST2, n2_w, n2_b, Mm + 131072, Hbf);
  k_gemm<<<dim3(32, 4, 32), 256, 0, stream>>>(W1, Hbf, fc1_b, G, nullptr, 192, 768, 1, 1);
  k_gemm<<<dim3(32, 1, 32), 256, 0, stream>>>(W2, G, fc2_b, out, out, 768, 192, 0, 2);
}